// Round 8
// baseline (236.125 us; speedup 1.0000x reference)
//
#include <hip/hip_runtime.h>
#include <hip/hip_bf16.h>

#define HW 16384
#define DIM 192
#define DIM2 384
#define NB 8
#define HEADS 8
#define CD 24
#define NSPLIT 64

typedef float f32x4 __attribute__((ext_vector_type(4)));
typedef short bf16x8 __attribute__((ext_vector_type(8)));
typedef short s16x4 __attribute__((ext_vector_type(4)));

__device__ __forceinline__ short f2bf(float f) {
    __hip_bfloat16 h = __float2bfloat16(f);
    return *reinterpret_cast<short*>(&h);
}
__device__ __forceinline__ float bf2f(short s) {
    __hip_bfloat16 h = *reinterpret_cast<__hip_bfloat16*>(&s);
    return __bfloat162float(h);
}

// ---------------------------------------------------------------------------
// prep: w1 (384x192 f32) -> bf16 packed in MFMA-fragment order:
// frag (mi,c,lane) at [(mi*6+c)*64+lane]*8, elem e = w1[mi*16+(l&15)][c*32+(l>>4)*8+e]
// ---------------------------------------------------------------------------
__global__ __launch_bounds__(256)
void prep_w1(const float* __restrict__ w1, short* __restrict__ wb1)
{
    int idx = blockIdx.x * 256 + threadIdx.x;      // < 24*6*64 = 9216
    if (idx >= 9216) return;
    int mi = idx / 384, rem = idx % 384;
    int c = rem >> 6, l = rem & 63;
    int oc = mi * 16 + (l & 15);
    int kb = c * 32 + (l >> 4) * 8;
    const float* src = w1 + (long)oc * DIM + kb;
    float4 v0 = *reinterpret_cast<const float4*>(src);
    float4 v1 = *reinterpret_cast<const float4*>(src + 4);
    bf16x8 o;
    o[0]=f2bf(v0.x); o[1]=f2bf(v0.y); o[2]=f2bf(v0.z); o[3]=f2bf(v0.w);
    o[4]=f2bf(v1.x); o[5]=f2bf(v1.y); o[6]=f2bf(v1.z); o[7]=f2bf(v1.w);
    *reinterpret_cast<bf16x8*>(wb1 + (long)idx * 8) = o;
}

// ---------------------------------------------------------------------------
// MFMA GEMM, K=192: C[b][oc][px] = sum_ic A[oc][ic] * B[b][ic][px].
// Block = 64-px slab x all OC (25.6 KB LDS -> 6 blocks/CU; grid 2048 -> deep
// cross-block overlap keeps HBM continuously fed). Single-shot staging (12
// vector loads/thread), transpose to [px][192k] stride-200 (bank-uniform
// without swizzle at this geometry), hoist 6 B-frags/wave to regs, then
// barrier-free A-ping-pong MFMA loop. Epilogue LDS aliases dead B-slab.
// ---------------------------------------------------------------------------
template<int NOCT, bool B_F32, bool PER_BATCH_A, bool OUT_F32>
__global__ __launch_bounds__(256, 5)
void gemm_k192(const short* __restrict__ Ab, const void* __restrict__ Bg,
               void* __restrict__ Cg, long bstrideB, long bstrideC)
{
    __shared__ short lds[64 * 200];      // B slab; epilogue aliases after hoist
    const int tid  = threadIdx.x;
    const int lane = tid & 63;
    const int wave = tid >> 6;
    const int px0  = blockIdx.x * 64;
    const int b    = blockIdx.y;

    const int row  = lane & 15;
    const int kgrp = lane >> 4;          // 0..3
    const short* A0 = Ab + (PER_BATCH_A ? (long)b * NOCT * 3072 : 0);

    bf16x8 aA[6], aB[6];
    auto loadA = [&](bf16x8* dst, int mi) {
#pragma unroll
        for (int c = 0; c < 6; c++)
            dst[c] = *reinterpret_cast<const bf16x8*>(
                &A0[((long)(mi * 6 + c) * 64 + lane) * 8]);
    };
    loadA(aA, 0);   // in flight alongside B staging

    // ---- single-shot stage: thread (q = px-quad 0..15, kl = k-lane 0..15) ----
    const int q  = tid & 15;             // px = 4q .. 4q+3
    const int kl = tid >> 4;             // k = 64g + 4kl + e
    {
        f32x4 stf[3][4];
        s16x4 sth[3][4];
        if constexpr (B_F32) {
            const float* src = (const float*)Bg + (long)b * bstrideB + px0 + q * 4;
#pragma unroll
            for (int g = 0; g < 3; g++)
#pragma unroll
                for (int e = 0; e < 4; e++)
                    stf[g][e] = *(const f32x4*)(src + (long)(64 * g + 4 * kl + e) * HW);
        } else {
            const short* src = (const short*)Bg + (long)b * bstrideB + px0 + q * 4;
#pragma unroll
            for (int g = 0; g < 3; g++)
#pragma unroll
                for (int e = 0; e < 4; e++)
                    sth[g][e] = *(const s16x4*)(src + (long)(64 * g + 4 * kl + e) * HW);
        }
#pragma unroll
        for (int g = 0; g < 3; g++)
#pragma unroll
            for (int i = 0; i < 4; i++) {
                s16x4 t;
                if constexpr (B_F32)
                    t = (s16x4){f2bf(stf[g][0][i]), f2bf(stf[g][1][i]),
                                f2bf(stf[g][2][i]), f2bf(stf[g][3][i])};
                else
                    t = (s16x4){sth[g][0][i], sth[g][1][i], sth[g][2][i], sth[g][3][i]};
                *(s16x4*)&lds[(q * 4 + i) * 200 + 64 * g + 4 * kl] = t;
            }
    }
    __syncthreads();

    // ---- hoist 6 B-fragments (wave covers px [wave*16, wave*16+16)) ----
    bf16x8 bv[6];
#pragma unroll
    for (int c = 0; c < 6; c++)
        bv[c] = *(const bf16x8*)&lds[(wave * 16 + row) * 200 + c * 32 + kgrp * 8];
    __syncthreads();                     // B-LDS dead; epilogue aliases it

    float* ep = reinterpret_cast<float*>(&lds[0]) + wave * 320;   // 16x20 f32/wave

    // ---- main loop: A ping-pong + MFMA; LDS-transpose epilogue ----
    const int ocl = lane >> 2;           // 0..15 (epilogue row)
    const int pxi = lane & 3;
    auto computeStore = [&](const bf16x8* a, int mi) {
        f32x4 acc = (f32x4){0.f, 0.f, 0.f, 0.f};
#pragma unroll
        for (int c = 0; c < 6; c++)
            acc = __builtin_amdgcn_mfma_f32_16x16x32_bf16(a[c], bv[c], acc, 0, 0, 0);
#pragma unroll
        for (int r = 0; r < 4; r++)
            ep[(kgrp * 4 + r) * 20 + row] = acc[r];
        // wave-internal LDS ordering (lgkmcnt) — no barrier needed
        f32x4 vv = *reinterpret_cast<const f32x4*>(&ep[ocl * 20 + pxi * 4]);
        long off = (long)b * bstrideC + (long)(mi * 16 + ocl) * HW
                 + px0 + wave * 16 + pxi * 4;
        if constexpr (OUT_F32) {
            __builtin_nontemporal_store(vv, reinterpret_cast<f32x4*>((float*)Cg + off));
        } else {
            *reinterpret_cast<s16x4*>((short*)Cg + off) =
                (s16x4){f2bf(vv[0]), f2bf(vv[1]), f2bf(vv[2]), f2bf(vv[3])};
        }
    };

    for (int mi = 0; mi < NOCT; mi += 2) {
        loadA(aB, mi + 1);
        computeStore(aA, mi);
        if (mi + 2 < NOCT) loadA(aA, mi + 2);
        computeStore(aB, mi + 1);
    }
}

// ---------------------------------------------------------------------------
// depthwise 3x3 (pad 1): register-rolling rows, NO LDS image.
// Thread (tx,ty) owns an 8x8 patch; halos via __shfl. Fused k sum-of-squares.
// ---------------------------------------------------------------------------
__global__ __launch_bounds__(256)
void dwconv_sumsq(const short* __restrict__ in, const float* __restrict__ w2,
                  short* __restrict__ outp, float* __restrict__ kss)
{
    __shared__ float red[4];
    const long bgc = blockIdx.x;           // b*384 + gc
    const int  gc  = (int)(bgc % DIM2);
    const int  b   = (int)(bgc / DIM2);
    const int  tid = threadIdx.x;
    const int  tx  = tid & 15;             // x-group: px [tx*8, tx*8+8)
    const int  ty  = tid >> 4;             // y-strip: rows [ty*8, ty*8+8)
    const int  lane = tid & 63;
    const int  x0 = tx * 8;
    const int  y0 = ty * 8;
    const short* src = in + (bgc << 14);
    short* dst = outp + (bgc << 14);

    float w[9];
#pragma unroll
    for (int i = 0; i < 9; i++) w[i] = w2[gc * 9 + i];   // wave-uniform -> SGPR

    float r0[10], r1[10], r2[10];
    auto loadRow = [&](float* r, int y) {
        if ((unsigned)y > 127u) {
#pragma unroll
            for (int i = 0; i < 10; i++) r[i] = 0.f;
            return;
        }
        bf16x8 v = *reinterpret_cast<const bf16x8*>(&src[y * 128 + x0]);
#pragma unroll
        for (int i = 0; i < 8; i++) r[i + 1] = bf2f(v[i]);
        float left  = __shfl(r[8], lane - 1);
        float right = __shfl(r[1], lane + 1);
        r[0] = (tx == 0)  ? 0.f : left;
        r[9] = (tx == 15) ? 0.f : right;
    };

    loadRow(r0, y0 - 1);
    loadRow(r1, y0);
    float ssq = 0.f;
#pragma unroll
    for (int k = 0; k < 8; k++) {
        const int yy = y0 + k;
        loadRow(r2, yy + 1);
        bf16x8 o;
#pragma unroll
        for (int j = 0; j < 8; j++) {
            float s = r0[j] * w[0] + r0[j + 1] * w[1] + r0[j + 2] * w[2]
                    + r1[j] * w[3] + r1[j + 1] * w[4] + r1[j + 2] * w[5]
                    + r2[j] * w[6] + r2[j + 1] * w[7] + r2[j + 2] * w[8];
            o[j] = f2bf(s);
            ssq += s * s;
        }
        *reinterpret_cast<bf16x8*>(&dst[yy * 128 + x0]) = o;
#pragma unroll
        for (int i = 0; i < 10; i++) { r0[i] = r1[i]; r1[i] = r2[i]; }
    }

    for (int o = 32; o; o >>= 1) ssq += __shfl_xor(ssq, o);
    if ((tid & 63) == 0) red[tid >> 6] = ssq;
    __syncthreads();
    if (gc < DIM && tid == 0)
        kss[b * DIM + gc] = red[0] + red[1] + red[2] + red[3];
}

// ---------------------------------------------------------------------------
// QK^T via MFMA over contiguous px. Zero LDS/transpose. Grid (NSPLIT, 64 bh);
// 1 wave computes 32x32 over HW/NSPLIT px. Fused q sumsq partials.
// ---------------------------------------------------------------------------
__global__ __launch_bounds__(64)
void qk_mfma(const float* __restrict__ q, const short* __restrict__ kvb,
             float* __restrict__ part, float* __restrict__ pssq)
{
    const int split = blockIdx.x;          // 0..NSPLIT-1
    const int bh    = blockIdx.y;          // b*8 + h
    const int b = bh >> 3, h = bh & 7;
    const int lane = threadIdx.x;
    const int row = lane & 15;
    const int kg  = (lane >> 4) * 8;
    const int CHUNK = HW / NSPLIT;         // 256

    const int qr1 = min(h * CD + 16 + row, DIM - 1);   // clamp (h=7 tail OOB)
    const float* q0 = q + ((long)b * DIM + h * CD + row) * HW + split * CHUNK + kg;
    const float* q1 = q + ((long)b * DIM + qr1) * HW + split * CHUNK + kg;
    const short* k0 = kvb + ((long)b * DIM2 + h * CD + row) * HW + split * CHUNK + kg;
    const short* k1 = k0 + 16L * HW;

    f32x4 acc[2][2];
#pragma unroll
    for (int m = 0; m < 2; m++)
#pragma unroll
        for (int n = 0; n < 2; n++) acc[m][n] = (f32x4){0.f, 0.f, 0.f, 0.f};
    float ssq0 = 0.f, ssq1 = 0.f;

#pragma unroll
    for (int s = 0; s < CHUNK / 32; s++) {
        const int px = s * 32;
        float4 qa = *reinterpret_cast<const float4*>(q0 + px);
        float4 qb = *reinterpret_cast<const float4*>(q0 + px + 4);
        float4 qc = *reinterpret_cast<const float4*>(q1 + px);
        float4 qd = *reinterpret_cast<const float4*>(q1 + px + 4);
        bf16x8 b0 = *reinterpret_cast<const bf16x8*>(k0 + px);
        bf16x8 b1 = *reinterpret_cast<const bf16x8*>(k1 + px);
        ssq0 += qa.x*qa.x + qa.y*qa.y + qa.z*qa.z + qa.w*qa.w
              + qb.x*qb.x + qb.y*qb.y + qb.z*qb.z + qb.w*qb.w;
        ssq1 += qc.x*qc.x + qc.y*qc.y + qc.z*qc.z + qc.w*qc.w
              + qd.x*qd.x + qd.y*qd.y + qd.z*qd.z + qd.w*qd.w;
        bf16x8 a0, a1;
        a0[0]=f2bf(qa.x); a0[1]=f2bf(qa.y); a0[2]=f2bf(qa.z); a0[3]=f2bf(qa.w);
        a0[4]=f2bf(qb.x); a0[5]=f2bf(qb.y); a0[6]=f2bf(qb.z); a0[7]=f2bf(qb.w);
        a1[0]=f2bf(qc.x); a1[1]=f2bf(qc.y); a1[2]=f2bf(qc.z); a1[3]=f2bf(qc.w);
        a1[4]=f2bf(qd.x); a1[5]=f2bf(qd.y); a1[6]=f2bf(qd.z); a1[7]=f2bf(qd.w);
        acc[0][0] = __builtin_amdgcn_mfma_f32_16x16x32_bf16(a0, b0, acc[0][0], 0, 0, 0);
        acc[0][1] = __builtin_amdgcn_mfma_f32_16x16x32_bf16(a0, b1, acc[0][1], 0, 0, 0);
        acc[1][0] = __builtin_amdgcn_mfma_f32_16x16x32_bf16(a1, b0, acc[1][0], 0, 0, 0);
        acc[1][1] = __builtin_amdgcn_mfma_f32_16x16x32_bf16(a1, b1, acc[1][1], 0, 0, 0);
    }

    ssq0 += __shfl_xor(ssq0, 16); ssq0 += __shfl_xor(ssq0, 32);
    ssq1 += __shfl_xor(ssq1, 16); ssq1 += __shfl_xor(ssq1, 32);

    float* pd = part + ((long)split * 64 + bh) * 576;
#pragma unroll
    for (int m = 0; m < 2; m++)
#pragma unroll
        for (int n = 0; n < 2; n++)
#pragma unroll
            for (int r = 0; r < 4; r++) {
                int c = m * 16 + (lane >> 4) * 4 + r;
                int d = n * 16 + row;
                if (c < CD && d < CD) pd[c * CD + d] = acc[m][n][r];
            }
    if (lane < 16) {
        float* ps = pssq + ((long)split * 64 + bh) * 32;
        ps[lane]      = ssq0;
        ps[16 + lane] = ssq1;
    }
}

// ---------------------------------------------------------------------------
// reduce split partials, normalize, scale, softmax over d (24)
// ---------------------------------------------------------------------------
__global__ __launch_bounds__(64)
void softmax_kernel(const float* __restrict__ part, const float* __restrict__ pssq,
                    const float* __restrict__ kss, const float* __restrict__ scale,
                    float* __restrict__ prob)
{
    const int blk = blockIdx.x;            // b*192 + h*24 + c
    const int b = blk / DIM;
    const int hc = blk % DIM;
    const int h = hc / CD, c = hc % CD;
    const int bh = b * 8 + h;
    const int d = threadIdx.x;

    float qs = 0.f;
    for (int s = 0; s < NSPLIT; s++) qs += pssq[((long)s * 64 + bh) * 32 + c];

    float val = -1e30f;
    if (d < CD) {
        float raw = 0.f;
        for (int s = 0; s < NSPLIT; s++) raw += part[((long)s * 64 + bh) * 576 + c * CD + d];
        float qn = fmaxf(sqrtf(qs), 1e-12f);
        float kn = fmaxf(sqrtf(kss[b * DIM + h * CD + d]), 1e-12f);
        val = raw * scale[h] / (qn * kn);
    }
    float m = val;
    for (int o = 32; o; o >>= 1) m = fmaxf(m, __shfl_xor(m, o));
    float e = (d < CD) ? expf(val - m) : 0.f;
    float s = e;
    for (int o = 32; o; o >>= 1) s += __shfl_xor(s, o);
    if (d < CD) prob[(long)blk * CD + d] = e / s;
}

// ---------------------------------------------------------------------------
// M[b] = pw @ blockdiag(attn[b]) in bf16, written directly in packed
// MFMA-fragment order: frag (b,mi,c,lane) elem e = M[mi*16+(l&15)][c*32+(l>>4)*8+e]
// ---------------------------------------------------------------------------
__global__ __launch_bounds__(256)
void buildm(const float* __restrict__ pw, const float* __restrict__ prob,
            short* __restrict__ M)
{
    int idx = blockIdx.x * 256 + threadIdx.x;      // < 8 * 12*6*64 = 36864
    if (idx >= 36864) return;
    int b   = idx / 4608, rem = idx % 4608;
    int mi  = rem / 384, r2 = rem % 384;
    int c   = r2 >> 6, l = r2 & 63;
    int oc  = mi * 16 + (l & 15);
    int gb  = c * 32 + (l >> 4) * 8;
    bf16x8 o;
#pragma unroll
    for (int e = 0; e < 8; e++) {
        int gvc = gb + e;
        int h = gvc / CD, d = gvc % CD;
        float s = 0.f;
#pragma unroll
        for (int cc = 0; cc < CD; cc++)
            s += pw[oc * DIM + h * CD + cc] * prob[((long)b * DIM + h * CD + cc) * CD + d];
        o[e] = f2bf(s);
    }
    *reinterpret_cast<bf16x8*>(M + (long)idx * 8) = o;
}

// ---------------------------------------------------------------------------
extern "C" void kernel_launch(void* const* d_in, const int* in_sizes, int n_in,
                              void* d_out, int out_size, void* d_ws, size_t ws_size,
                              hipStream_t stream)
{
    const float* kv    = (const float*)d_in[0];
    const float* q     = (const float*)d_in[1];
    const float* w1    = (const float*)d_in[2];   // (384,192)
    const float* w2    = (const float*)d_in[3];   // (384,9)
    const float* pw    = (const float*)d_in[4];   // (192,192)
    const float* scale = (const float*)d_in[5];   // (8)
    float* out = (float*)d_out;

    char* ws = (char*)d_ws;
    long off = 0;
    auto alloc = [&](long bytes) { char* p = ws + off; off += (bytes + 255) & ~255L; return p; };
    short* kvf1 = (short*)alloc((long)NB * DIM2 * HW * 2);   // 96 MiB
    short* kvb  = (short*)alloc((long)NB * DIM2 * HW * 2);   // 96 MiB
    short* wb1  = (short*)alloc((long)DIM2 * DIM * 2);
    float* kss  = (float*)alloc((long)NB * DIM * 4);
    float* part = (float*)alloc((long)NSPLIT * 64 * 576 * 4);
    float* pssq = (float*)alloc((long)NSPLIT * 64 * 32 * 4);
    float* prob = (float*)alloc((long)64 * 576 * 4);
    short* M    = (short*)alloc((long)NB * DIM * DIM * 2);

    // 1) w1 -> bf16, packed fragment order
    prep_w1<<<36, 256, 0, stream>>>(w1, wb1);

    // 2) 1x1 conv (GEMM): kvf1 = w1 @ kv, bf16 out
    gemm_k192<24, true, false, false><<<dim3(256, NB), 256, 0, stream>>>(
        wb1, kv, kvf1, (long)DIM * HW, (long)DIM2 * HW);

    // 3) depthwise 3x3 + k sumsq (register-rolling, no LDS)
    dwconv_sumsq<<<NB * DIM2, 256, 0, stream>>>(kvf1, w2, kvb, kss);

    // 4) QK^T partials + q sumsq partials (MFMA over px)
    qk_mfma<<<dim3(NSPLIT, 64), 64, 0, stream>>>(q, kvb, part, pssq);

    // 5) softmax
    softmax_kernel<<<NB * DIM, 64, 0, stream>>>(part, pssq, kss, scale, prob);

    // 6) fold proj into attention: M[b] packed in fragment order, bf16
    buildm<<<144, 256, 0, stream>>>(pw, prob, M);

    // 7) out = M[b] @ v  (PV + proj fused), f32 out
    gemm_k192<12, false, true, true><<<dim3(256, NB), 256, 0, stream>>>(
        M, kvb + (long)DIM * HW, out, (long)DIM2 * HW, (long)DIM * HW);
}

// Round 9
// 179.435 us; speedup vs baseline: 1.3159x; 1.3159x over previous
//
#include <hip/hip_runtime.h>
#include <hip/hip_bf16.h>

#define HW 16384
#define DIM 192
#define DIM2 384
#define NB 8
#define HEADS 8
#define CD 24
#define NSPLIT 64

typedef float f32x4 __attribute__((ext_vector_type(4)));
typedef short bf16x8 __attribute__((ext_vector_type(8)));
typedef short s16x4 __attribute__((ext_vector_type(4)));

__device__ __forceinline__ short f2bf(float f) {
    __hip_bfloat16 h = __float2bfloat16(f);
    return *reinterpret_cast<short*>(&h);
}
__device__ __forceinline__ float bf2f(short s) {
    __hip_bfloat16 h = *reinterpret_cast<__hip_bfloat16*>(&s);
    return __bfloat162float(h);
}

// ---------------------------------------------------------------------------
// prep: w1 (384x192 f32) -> bf16 packed in MFMA-fragment order:
// frag (mi,c,lane) at [(mi*6+c)*64+lane]*8, elem e = w1[mi*16+(l&15)][c*32+(l>>4)*8+e]
// ---------------------------------------------------------------------------
__global__ __launch_bounds__(256)
void prep_w1(const float* __restrict__ w1, short* __restrict__ wb1)
{
    int idx = blockIdx.x * 256 + threadIdx.x;      // < 24*6*64 = 9216
    if (idx >= 9216) return;
    int mi = idx / 384, rem = idx % 384;
    int c = rem >> 6, l = rem & 63;
    int oc = mi * 16 + (l & 15);
    int kb = c * 32 + (l >> 4) * 8;
    const float* src = w1 + (long)oc * DIM + kb;
    float4 v0 = *reinterpret_cast<const float4*>(src);
    float4 v1 = *reinterpret_cast<const float4*>(src + 4);
    bf16x8 o;
    o[0]=f2bf(v0.x); o[1]=f2bf(v0.y); o[2]=f2bf(v0.z); o[3]=f2bf(v0.w);
    o[4]=f2bf(v1.x); o[5]=f2bf(v1.y); o[6]=f2bf(v1.z); o[7]=f2bf(v1.w);
    *reinterpret_cast<bf16x8*>(wb1 + (long)idx * 8) = o;
}

// ---------------------------------------------------------------------------
// MFMA GEMM, K=192: C[b][oc][px] = sum_ic A[oc][ic] * B[b][ic][px].
// Block = TWO 128-px slabs, slab-level software pipeline:
//   stage0 -> hoist0 -> [issue stage1 loads] compute0 -> write1 -> hoist1
//   -> compute1.   Slab1's HBM reads overlap slab0's entire compute phase.
// Staging regs stay in flight (96 VGPR f32 path) -> launch_bounds(256,2).
// Separate epilogue LDS (B-slab must stay writable for slab1). Grid 512 =
// one launch round at 2 blocks/CU.
// ---------------------------------------------------------------------------
template<int NOCT, bool B_F32, bool PER_BATCH_A, bool OUT_F32>
__global__ __launch_bounds__(256, 2)
void gemm_k192(const short* __restrict__ Ab, const void* __restrict__ Bg,
               void* __restrict__ Cg, long bstrideB, long bstrideC)
{
    __shared__ short lds[128 * 200];     // B slab (51.2 KB)
    __shared__ float eps[4][16 * 36];    // epilogue transpose buf (9 KB)
    const int tid  = threadIdx.x;
    const int lane = tid & 63;
    const int wave = tid >> 6;
    const int pxbase = blockIdx.x * 256; // two 128-px slabs per block
    const int b    = blockIdx.y;

    const int row  = lane & 15;
    const int kgrp = lane >> 4;          // 0..3
    const short* A0 = Ab + (PER_BATCH_A ? (long)b * NOCT * 3072 : 0);

    bf16x8 aA[6], aB[6];
    auto loadA = [&](bf16x8* dst, int mi) {
#pragma unroll
        for (int c = 0; c < 6; c++)
            dst[c] = *reinterpret_cast<const bf16x8*>(
                &A0[((long)(mi * 6 + c) * 64 + lane) * 8]);
    };

    // ---- staging: thread (q = px-quad 0..31, kl = k-lane 0..7) ----
    const int q  = tid & 31;             // px = 4q .. 4q+3
    const int kl = tid >> 5;             // k = 32j + 4kl + e
    f32x4 stf[6][4];
    s16x4 sth[6][4];
    auto SLOAD = [&](int px0) {          // issue 24 vector loads (kept in regs)
        if constexpr (B_F32) {
            const float* src = (const float*)Bg + (long)b * bstrideB + px0 + q * 4;
#pragma unroll
            for (int j = 0; j < 6; j++)
#pragma unroll
                for (int e = 0; e < 4; e++)
                    stf[j][e] = __builtin_nontemporal_load(
                        reinterpret_cast<const f32x4*>(src + (long)(32 * j + 4 * kl + e) * HW));
        } else {
            const short* src = (const short*)Bg + (long)b * bstrideB + px0 + q * 4;
#pragma unroll
            for (int j = 0; j < 6; j++)
#pragma unroll
                for (int e = 0; e < 4; e++)
                    sth[j][e] = __builtin_nontemporal_load(
                        reinterpret_cast<const s16x4*>(src + (long)(32 * j + 4 * kl + e) * HW));
        }
    };
    auto SWRITE = [&]() {                // cvt + transpose + swizzled LDS write
        const int goff = (((kl >> 1) ^ (q & 3)) << 3) + (kl & 1) * 4;
#pragma unroll
        for (int j = 0; j < 6; j++) {
#pragma unroll
            for (int i = 0; i < 4; i++) {
                s16x4 t;
                if constexpr (B_F32)
                    t = (s16x4){f2bf(stf[j][0][i]), f2bf(stf[j][1][i]),
                                f2bf(stf[j][2][i]), f2bf(stf[j][3][i])};
                else
                    t = (s16x4){sth[j][0][i], sth[j][1][i], sth[j][2][i], sth[j][3][i]};
                *(s16x4*)&lds[(q * 4 + i) * 200 + 32 * j + goff] = t;
            }
        }
    };

    bf16x8 bv[2][6];
    auto HOIST = [&]() {                 // 12 B-frags -> regs
        const int bro = wave * 32 + row;
        const int sgr = (row >> 2) & 3;
#pragma unroll
        for (int c = 0; c < 6; c++) {
            bv[0][c] = *(const bf16x8*)&lds[bro * 200 + c * 32 + ((kgrp ^ sgr) << 3)];
            bv[1][c] = *(const bf16x8*)&lds[(bro + 16) * 200 + c * 32 + ((kgrp ^ sgr) << 3)];
        }
    };

    const int ocl = lane >> 2;           // 0..15 (epilogue row)
    float* ep = &eps[wave][0];
    auto computeStore = [&](const bf16x8* a, int mi, int px0) {
        f32x4 acc0 = (f32x4){0.f, 0.f, 0.f, 0.f};
        f32x4 acc1 = (f32x4){0.f, 0.f, 0.f, 0.f};
#pragma unroll
        for (int c = 0; c < 6; c++) {
            acc0 = __builtin_amdgcn_mfma_f32_16x16x32_bf16(a[c], bv[0][c], acc0, 0, 0, 0);
            acc1 = __builtin_amdgcn_mfma_f32_16x16x32_bf16(a[c], bv[1][c], acc1, 0, 0, 0);
        }
#pragma unroll
        for (int r = 0; r < 4; r++) {
            ep[(kgrp * 4 + r) * 36 + row]      = acc0[r];
            ep[(kgrp * 4 + r) * 36 + 16 + row] = acc1[r];
        }
        // wave-internal LDS ordering (lgkmcnt) — no barrier needed
#pragma unroll
        for (int t = 0; t < 2; t++) {
            const int pxq = (lane & 3) + t * 4;          // 0..7
            f32x4 vv = *reinterpret_cast<const f32x4*>(&ep[ocl * 36 + pxq * 4]);
            long off = (long)b * bstrideC + (long)(mi * 16 + ocl) * HW
                     + px0 + wave * 32 + pxq * 4;
            if constexpr (OUT_F32) {
                __builtin_nontemporal_store(vv, reinterpret_cast<f32x4*>((float*)Cg + off));
            } else {
                *reinterpret_cast<s16x4*>((short*)Cg + off) =
                    (s16x4){f2bf(vv[0]), f2bf(vv[1]), f2bf(vv[2]), f2bf(vv[3])};
            }
        }
    };
    auto COMPUTE = [&](int px0) {        // expects aA preloaded with mi=0
        for (int mi = 0; mi < NOCT; mi += 2) {
            loadA(aB, mi + 1);
            computeStore(aA, mi, px0);
            if (mi + 2 < NOCT) loadA(aA, mi + 2);
            computeStore(aB, mi + 1, px0);
        }
    };

    // ---- slab pipeline ----
    loadA(aA, 0);
    SLOAD(pxbase);            // slab0
    SWRITE();
    __syncthreads();
    HOIST();
    __syncthreads();          // all waves past hoist -> B-LDS reusable
    SLOAD(pxbase + 128);      // slab1 loads in flight during compute0
    COMPUTE(pxbase);
    loadA(aA, 0);             // re-arm A for slab1
    SWRITE();                 // waits on slab1 loads (counted vmcnt)
    __syncthreads();
    HOIST();
    COMPUTE(pxbase + 128);
}

// ---------------------------------------------------------------------------
// depthwise 3x3 (pad 1): register-rolling rows, NO LDS image.
// Thread (tx,ty) owns an 8x8 patch; halos via __shfl. Fused k sum-of-squares.
// ---------------------------------------------------------------------------
__global__ __launch_bounds__(256)
void dwconv_sumsq(const short* __restrict__ in, const float* __restrict__ w2,
                  short* __restrict__ outp, float* __restrict__ kss)
{
    __shared__ float red[4];
    const long bgc = blockIdx.x;           // b*384 + gc
    const int  gc  = (int)(bgc % DIM2);
    const int  b   = (int)(bgc / DIM2);
    const int  tid = threadIdx.x;
    const int  tx  = tid & 15;             // x-group: px [tx*8, tx*8+8)
    const int  ty  = tid >> 4;             // y-strip: rows [ty*8, ty*8+8)
    const int  lane = tid & 63;
    const int  x0 = tx * 8;
    const int  y0 = ty * 8;
    const short* src = in + (bgc << 14);
    short* dst = outp + (bgc << 14);

    float w[9];
#pragma unroll
    for (int i = 0; i < 9; i++) w[i] = w2[gc * 9 + i];   // wave-uniform -> SGPR

    float r0[10], r1[10], r2[10];
    auto loadRow = [&](float* r, int y) {
        if ((unsigned)y > 127u) {
#pragma unroll
            for (int i = 0; i < 10; i++) r[i] = 0.f;
            return;
        }
        bf16x8 v = *reinterpret_cast<const bf16x8*>(&src[y * 128 + x0]);
#pragma unroll
        for (int i = 0; i < 8; i++) r[i + 1] = bf2f(v[i]);
        float left  = __shfl(r[8], lane - 1);
        float right = __shfl(r[1], lane + 1);
        r[0] = (tx == 0)  ? 0.f : left;
        r[9] = (tx == 15) ? 0.f : right;
    };

    loadRow(r0, y0 - 1);
    loadRow(r1, y0);
    float ssq = 0.f;
#pragma unroll
    for (int k = 0; k < 8; k++) {
        const int yy = y0 + k;
        loadRow(r2, yy + 1);
        bf16x8 o;
#pragma unroll
        for (int j = 0; j < 8; j++) {
            float s = r0[j] * w[0] + r0[j + 1] * w[1] + r0[j + 2] * w[2]
                    + r1[j] * w[3] + r1[j + 1] * w[4] + r1[j + 2] * w[5]
                    + r2[j] * w[6] + r2[j + 1] * w[7] + r2[j + 2] * w[8];
            o[j] = f2bf(s);
            ssq += s * s;
        }
        *reinterpret_cast<bf16x8*>(&dst[yy * 128 + x0]) = o;
#pragma unroll
        for (int i = 0; i < 10; i++) { r0[i] = r1[i]; r1[i] = r2[i]; }
    }

    for (int o = 32; o; o >>= 1) ssq += __shfl_xor(ssq, o);
    if ((tid & 63) == 0) red[tid >> 6] = ssq;
    __syncthreads();
    if (gc < DIM && tid == 0)
        kss[b * DIM + gc] = red[0] + red[1] + red[2] + red[3];
}

// ---------------------------------------------------------------------------
// QK^T via MFMA over contiguous px. Zero LDS/transpose. Grid (NSPLIT, 64 bh);
// 1 wave computes 32x32 over HW/NSPLIT px. Fused q sumsq partials.
// ---------------------------------------------------------------------------
__global__ __launch_bounds__(64)
void qk_mfma(const float* __restrict__ q, const short* __restrict__ kvb,
             float* __restrict__ part, float* __restrict__ pssq)
{
    const int split = blockIdx.x;          // 0..NSPLIT-1
    const int bh    = blockIdx.y;          // b*8 + h
    const int b = bh >> 3, h = bh & 7;
    const int lane = threadIdx.x;
    const int row = lane & 15;
    const int kg  = (lane >> 4) * 8;
    const int CHUNK = HW / NSPLIT;         // 256

    const int qr1 = min(h * CD + 16 + row, DIM - 1);   // clamp (h=7 tail OOB)
    const float* q0 = q + ((long)b * DIM + h * CD + row) * HW + split * CHUNK + kg;
    const float* q1 = q + ((long)b * DIM + qr1) * HW + split * CHUNK + kg;
    const short* k0 = kvb + ((long)b * DIM2 + h * CD + row) * HW + split * CHUNK + kg;
    const short* k1 = k0 + 16L * HW;

    f32x4 acc[2][2];
#pragma unroll
    for (int m = 0; m < 2; m++)
#pragma unroll
        for (int n = 0; n < 2; n++) acc[m][n] = (f32x4){0.f, 0.f, 0.f, 0.f};
    float ssq0 = 0.f, ssq1 = 0.f;

#pragma unroll
    for (int s = 0; s < CHUNK / 32; s++) {
        const int px = s * 32;
        float4 qa = *reinterpret_cast<const float4*>(q0 + px);
        float4 qb = *reinterpret_cast<const float4*>(q0 + px + 4);
        float4 qc = *reinterpret_cast<const float4*>(q1 + px);
        float4 qd = *reinterpret_cast<const float4*>(q1 + px + 4);
        bf16x8 b0 = *reinterpret_cast<const bf16x8*>(k0 + px);
        bf16x8 b1 = *reinterpret_cast<const bf16x8*>(k1 + px);
        ssq0 += qa.x*qa.x + qa.y*qa.y + qa.z*qa.z + qa.w*qa.w
              + qb.x*qb.x + qb.y*qb.y + qb.z*qb.z + qb.w*qb.w;
        ssq1 += qc.x*qc.x + qc.y*qc.y + qc.z*qc.z + qc.w*qc.w
              + qd.x*qd.x + qd.y*qd.y + qd.z*qd.z + qd.w*qd.w;
        bf16x8 a0, a1;
        a0[0]=f2bf(qa.x); a0[1]=f2bf(qa.y); a0[2]=f2bf(qa.z); a0[3]=f2bf(qa.w);
        a0[4]=f2bf(qb.x); a0[5]=f2bf(qb.y); a0[6]=f2bf(qb.z); a0[7]=f2bf(qb.w);
        a1[0]=f2bf(qc.x); a1[1]=f2bf(qc.y); a1[2]=f2bf(qc.z); a1[3]=f2bf(qc.w);
        a1[4]=f2bf(qd.x); a1[5]=f2bf(qd.y); a1[6]=f2bf(qd.z); a1[7]=f2bf(qd.w);
        acc[0][0] = __builtin_amdgcn_mfma_f32_16x16x32_bf16(a0, b0, acc[0][0], 0, 0, 0);
        acc[0][1] = __builtin_amdgcn_mfma_f32_16x16x32_bf16(a0, b1, acc[0][1], 0, 0, 0);
        acc[1][0] = __builtin_amdgcn_mfma_f32_16x16x32_bf16(a1, b0, acc[1][0], 0, 0, 0);
        acc[1][1] = __builtin_amdgcn_mfma_f32_16x16x32_bf16(a1, b1, acc[1][1], 0, 0, 0);
    }

    ssq0 += __shfl_xor(ssq0, 16); ssq0 += __shfl_xor(ssq0, 32);
    ssq1 += __shfl_xor(ssq1, 16); ssq1 += __shfl_xor(ssq1, 32);

    float* pd = part + ((long)split * 64 + bh) * 576;
#pragma unroll
    for (int m = 0; m < 2; m++)
#pragma unroll
        for (int n = 0; n < 2; n++)
#pragma unroll
            for (int r = 0; r < 4; r++) {
                int c = m * 16 + (lane >> 4) * 4 + r;
                int d = n * 16 + row;
                if (c < CD && d < CD) pd[c * CD + d] = acc[m][n][r];
            }
    if (lane < 16) {
        float* ps = pssq + ((long)split * 64 + bh) * 32;
        ps[lane]      = ssq0;
        ps[16 + lane] = ssq1;
    }
}

// ---------------------------------------------------------------------------
// reduce split partials, normalize, scale, softmax over d (24)
// ---------------------------------------------------------------------------
__global__ __launch_bounds__(64)
void softmax_kernel(const float* __restrict__ part, const float* __restrict__ pssq,
                    const float* __restrict__ kss, const float* __restrict__ scale,
                    float* __restrict__ prob)
{
    const int blk = blockIdx.x;            // b*192 + h*24 + c
    const int b = blk / DIM;
    const int hc = blk % DIM;
    const int h = hc / CD, c = hc % CD;
    const int bh = b * 8 + h;
    const int d = threadIdx.x;

    float qs = 0.f;
    for (int s = 0; s < NSPLIT; s++) qs += pssq[((long)s * 64 + bh) * 32 + c];

    float val = -1e30f;
    if (d < CD) {
        float raw = 0.f;
        for (int s = 0; s < NSPLIT; s++) raw += part[((long)s * 64 + bh) * 576 + c * CD + d];
        float qn = fmaxf(sqrtf(qs), 1e-12f);
        float kn = fmaxf(sqrtf(kss[b * DIM + h * CD + d]), 1e-12f);
        val = raw * scale[h] / (qn * kn);
    }
    float m = val;
    for (int o = 32; o; o >>= 1) m = fmaxf(m, __shfl_xor(m, o));
    float e = (d < CD) ? expf(val - m) : 0.f;
    float s = e;
    for (int o = 32; o; o >>= 1) s += __shfl_xor(s, o);
    if (d < CD) prob[(long)blk * CD + d] = e / s;
}

// ---------------------------------------------------------------------------
// M[b] = pw @ blockdiag(attn[b]) in bf16, written directly in packed
// MFMA-fragment order: frag (b,mi,c,lane) elem e = M[mi*16+(l&15)][c*32+(l>>4)*8+e]
// ---------------------------------------------------------------------------
__global__ __launch_bounds__(256)
void buildm(const float* __restrict__ pw, const float* __restrict__ prob,
            short* __restrict__ M)
{
    int idx = blockIdx.x * 256 + threadIdx.x;      // < 8 * 12*6*64 = 36864
    if (idx >= 36864) return;
    int b   = idx / 4608, rem = idx % 4608;
    int mi  = rem / 384, r2 = rem % 384;
    int c   = r2 >> 6, l = r2 & 63;
    int oc  = mi * 16 + (l & 15);
    int gb  = c * 32 + (l >> 4) * 8;
    bf16x8 o;
#pragma unroll
    for (int e = 0; e < 8; e++) {
        int gvc = gb + e;
        int h = gvc / CD, d = gvc % CD;
        float s = 0.f;
#pragma unroll
        for (int cc = 0; cc < CD; cc++)
            s += pw[oc * DIM + h * CD + cc] * prob[((long)b * DIM + h * CD + cc) * CD + d];
        o[e] = f2bf(s);
    }
    *reinterpret_cast<bf16x8*>(M + (long)idx * 8) = o;
}

// ---------------------------------------------------------------------------
extern "C" void kernel_launch(void* const* d_in, const int* in_sizes, int n_in,
                              void* d_out, int out_size, void* d_ws, size_t ws_size,
                              hipStream_t stream)
{
    const float* kv    = (const float*)d_in[0];
    const float* q     = (const float*)d_in[1];
    const float* w1    = (const float*)d_in[2];   // (384,192)
    const float* w2    = (const float*)d_in[3];   // (384,9)
    const float* pw    = (const float*)d_in[4];   // (192,192)
    const float* scale = (const float*)d_in[5];   // (8)
    float* out = (float*)d_out;

    char* ws = (char*)d_ws;
    long off = 0;
    auto alloc = [&](long bytes) { char* p = ws + off; off += (bytes + 255) & ~255L; return p; };
    short* kvf1 = (short*)alloc((long)NB * DIM2 * HW * 2);   // 96 MiB
    short* kvb  = (short*)alloc((long)NB * DIM2 * HW * 2);   // 96 MiB
    short* wb1  = (short*)alloc((long)DIM2 * DIM * 2);
    float* kss  = (float*)alloc((long)NB * DIM * 4);
    float* part = (float*)alloc((long)NSPLIT * 64 * 576 * 4);
    float* pssq = (float*)alloc((long)NSPLIT * 64 * 32 * 4);
    float* prob = (float*)alloc((long)64 * 576 * 4);
    short* M    = (short*)alloc((long)NB * DIM * DIM * 2);

    // 1) w1 -> bf16, packed fragment order
    prep_w1<<<36, 256, 0, stream>>>(w1, wb1);

    // 2) 1x1 conv (GEMM): kvf1 = w1 @ kv, bf16 out  (2 slabs/block)
    gemm_k192<24, true, false, false><<<dim3(64, NB), 256, 0, stream>>>(
        wb1, kv, kvf1, (long)DIM * HW, (long)DIM2 * HW);

    // 3) depthwise 3x3 + k sumsq (register-rolling, no LDS)
    dwconv_sumsq<<<NB * DIM2, 256, 0, stream>>>(kvf1, w2, kvb, kss);

    // 4) QK^T partials + q sumsq partials (MFMA over px)
    qk_mfma<<<dim3(NSPLIT, 64), 64, 0, stream>>>(q, kvb, part, pssq);

    // 5) softmax
    softmax_kernel<<<NB * DIM, 64, 0, stream>>>(part, pssq, kss, scale, prob);

    // 6) fold proj into attention: M[b] packed in fragment order, bf16
    buildm<<<144, 256, 0, stream>>>(pw, prob, M);

    // 7) out = M[b] @ v  (PV + proj fused), f32 out  (2 slabs/block)
    gemm_k192<12, false, true, true><<<dim3(64, NB), 256, 0, stream>>>(
        M, kvb + (long)DIM * HW, out, (long)DIM2 * HW, (long)DIM * HW);
}